// Round 12
// baseline (284.335 us; speedup 1.0000x reference)
//
#include <hip/hip_runtime.h>
#include <math.h>

#define DIM 128
#define NCH 32          // edge chunks; per-chunk per-node count < 65536 -> u16
#define NMAXW 25024     // LDS histogram words (covers N <= 50048)

typedef float f32x4v __attribute__((ext_vector_type(4)));
typedef short bf16x8 __attribute__((ext_vector_type(8)));

static __device__ __forceinline__ short f2bf(float f) {
    unsigned u = __float_as_uint(f);
    unsigned r = (u + 0x7fffu + ((u >> 16) & 1u)) >> 16;   // RNE
    return (short)r;
}
static __device__ __forceinline__ float bf2f(unsigned short s) {
    return __uint_as_float(((unsigned)s) << 16);
}

// ---------------------------------------------------------------------------
// K1: ONE-PASS full-N LDS histogram per edge chunk (u16 packed counters).
// Per-chunk counts < 65536 -> full-N u16 histogram = 100 KB LDS. Packed u16
// atomics on u32 words (halves can't carry: each half < 2^16). Blocks
// [0,NCH): dst histogram + rank (dense coalesced u16 write); [NCH,2NCH):
// src histogram. Edge reads: 6.4 MB, once.
// (R11's merged wconv/bsum variant regressed ~13 us — every block inherited
// the 100 KB static LDS and the hist critical path grew. Kept standalone.)
__global__ __launch_bounds__(1024) void k_hist(const int* __restrict__ src,
                                               const int* __restrict__ dst,
                                               unsigned short* __restrict__ partO,
                                               unsigned short* __restrict__ partI,
                                               unsigned short* __restrict__ rank,
                                               int N, int Npad, int E, int chunk) {
    __shared__ unsigned int h[NMAXW];
    int t = threadIdx.x;
    int isI = blockIdx.x < NCH;
    int c = isI ? blockIdx.x : blockIdx.x - NCH;
    int NW = (N + 1) >> 1;
    for (int i = t; i < NW; i += 1024) h[i] = 0;
    __syncthreads();
    int e0 = c * chunk, e1 = min(e0 + chunk, E);
    if (isI) {
        for (int e = e0 + t; e < e1; e += 1024) {
            int d = dst[e];
            unsigned sh = (d & 1) * 16;
            unsigned old = atomicAdd(&h[d >> 1], 1u << sh);   // LDS atomic
            rank[e] = (unsigned short)((old >> sh) & 0xffffu);
        }
    } else {
        for (int e = e0 + t; e < e1; e += 1024) {
            int s = src[e];
            atomicAdd(&h[s >> 1], 1u << ((s & 1) * 16));
        }
    }
    __syncthreads();
    unsigned int* p = (unsigned int*)((isI ? partI : partO) + (size_t)c * Npad);
    for (int i = t; i < NW; i += 1024) p[i] = h[i];   // u16 pair per word
}

// K2: per-256-node block sums of degI (over the NCH chunk partials).
__global__ __launch_bounds__(256) void k_bsum(const unsigned short* __restrict__ partI,
                                              int* __restrict__ bsum, int N, int Npad) {
    __shared__ int red[4];
    int b = blockIdx.x, t = threadIdx.x;
    int n = b * 256 + t;
    int s = 0;
    if (n < N) {
        #pragma unroll
        for (int c = 0; c < NCH; ++c) s += partI[(size_t)c * Npad + n];
    }
    for (int off = 32; off; off >>= 1) s += __shfl_down(s, off);
    if ((t & 63) == 0) red[t >> 6] = s;
    __syncthreads();
    if (t == 0) bsum[b] = red[0] + red[1] + red[2] + red[3];
}

// K3: exclusive scan -> csrOff + per-chunk bases csrOffC + norm factors.
// One node per thread, NB <= 256 blocks, LDS Hillis-Steele scans.
__global__ __launch_bounds__(256) void k_off(const unsigned short* __restrict__ partI,
                                             const unsigned short* __restrict__ partO,
                                             const int* __restrict__ bsum,
                                             int* __restrict__ csrOffC,
                                             int* __restrict__ csrOff,
                                             float* __restrict__ normIf,
                                             float* __restrict__ normOf,
                                             int N, int Npad, int NB) {
    __shared__ int sp[256];
    __shared__ int sbase;
    int b = blockIdx.x, t = threadIdx.x;
    int own = (t < NB) ? bsum[t] : 0;
    sp[t] = own;
    __syncthreads();
    for (int off = 1; off < 256; off <<= 1) {
        int u = (t >= off) ? sp[t - off] : 0;
        __syncthreads();
        sp[t] += u;
        __syncthreads();
    }
    if (t == b) sbase = sp[t] - own;
    if (b == 0 && t == NB - 1) csrOff[N] = sp[t];
    __syncthreads();
    int n = b * 256 + t;
    int cv[NCH];
    int tI = 0, tO = 0;
    if (n < N) {
        #pragma unroll
        for (int c = 0; c < NCH; ++c) {
            cv[c] = partI[(size_t)c * Npad + n];
            tI += cv[c];
            tO += partO[(size_t)c * Npad + n];
        }
    }
    sp[t] = tI;
    __syncthreads();
    for (int off = 1; off < 256; off <<= 1) {
        int u = (t >= off) ? sp[t - off] : 0;
        __syncthreads();
        sp[t] += u;
        __syncthreads();
    }
    int o = sbase + sp[t] - tI;
    if (n < N) {
        csrOff[n] = o;
        normIf[n] = rsqrtf(fmaxf((float)tI, 1.0f));
        normOf[n] = rsqrtf(fmaxf((float)tO, 1.0f));
        int base = o;
        #pragma unroll
        for (int c = 0; c < NCH; ++c) {
            csrOffC[(size_t)c * N + n] = base;
            base += cv[c];
        }
    }
}

// K4: merged pre-scaled bf16 feat/hx + bf16 weight convert.
__global__ __launch_bounds__(256) void k_xcw(const float* __restrict__ feat,
                                             const float* __restrict__ hx,
                                             const float* __restrict__ Wi,
                                             const float* __restrict__ Wh,
                                             const float* __restrict__ normOf,
                                             short* __restrict__ Wbf,
                                             short* __restrict__ fh, int N) {
    int i = blockIdx.x * 256 + threadIdx.x;
    int T1 = N * 64;
    if (i < T1) {
        int n = i >> 6, q = i & 63;
        float ns = normOf[n];
        const float* spp = (q < 32) ? &feat[(size_t)n * 128 + q * 4]
                                    : &hx[(size_t)n * 128 + (q - 32) * 4];
        float4 v = *(const float4*)spp;
        short4 p;
        p.x = f2bf(v.x * ns); p.y = f2bf(v.y * ns);
        p.z = f2bf(v.z * ns); p.w = f2bf(v.w * ns);
        *(short4*)&fh[(size_t)n * 256 + q * 4] = p;   // q*4 == 128+(q-32)*4
    } else {
        int w = i - T1;
        if (w < 98304) {
            int k = w & 127, n = (w >> 7) & 15, r = w >> 11;
            int gm = r % 6, cb = r / 6;
            const float* Wsrc = (gm < 3) ? Wi : Wh;
            int g = gm % 3;
            Wbf[w] = f2bf(Wsrc[k * 384 + g * 128 + cb * 16 + n]);
        }
    }
}

// K5: atomic-free counting-sort fill (pos = csrOffC[e/chunk][dst] + rank).
__global__ __launch_bounds__(256) void k_fill(const int* __restrict__ src,
                                              const int* __restrict__ dst,
                                              const unsigned short* __restrict__ rank,
                                              const int* __restrict__ csrOffC,
                                              int* __restrict__ srcSorted,
                                              int N, int E, int chunk) {
    int e = blockIdx.x * 256 + threadIdx.x;
    if (e < E) {
        int c = e / chunk;
        int pos = csrOffC[(size_t)c * N + dst[e]] + (int)rank[e];
        srcSorted[pos] = src[e];
    }
}

// ---------------------------------------------------------------------------
// K6: gather-aggregate. R1 form, FROZEN: one wave per dst node, 12500 blocks,
// wave-uniform scalar index loads, 8 B/lane row reads, 28 VGPR. Five
// structural variants (half-wave split R2, explicit batch R3, shfl-broadcast
// R7, grid-stride R10) were all neutral or regressed — high TLP plus this
// exact chain is the measured floor (~65 us, 214 MB compulsory L2-miss).
__global__ __launch_bounds__(256) void gather_kernel(
    const short* __restrict__ fh, const int* __restrict__ csrOff,
    const int* __restrict__ srcSorted, const float* __restrict__ normIf,
    short* __restrict__ agg, int N) {
    int wv = threadIdx.x >> 6, lane = threadIdx.x & 63;
    int d = blockIdx.x * 4 + wv;
    if (d >= N) return;
    const ushort4* fh4 = (const ushort4*)fh;
    int beg = csrOff[d], end = csrOff[d + 1];
    float4 acc = make_float4(0.f, 0.f, 0.f, 0.f);
    #pragma unroll 8
    for (int e = beg; e < end; ++e) {
        int s = srcSorted[e];                     // wave-uniform scalar load
        ushort4 v = fh4[(size_t)s * 64 + lane];   // 8B/lane, 512B/wave
        acc.x += bf2f(v.x); acc.y += bf2f(v.y);
        acc.z += bf2f(v.z); acc.w += bf2f(v.w);
    }
    float nd = normIf[d];
    short4 p;
    p.x = f2bf(acc.x * nd); p.y = f2bf(acc.y * nd);
    p.z = f2bf(acc.z * nd); p.w = f2bf(acc.w * nd);
    *(short4*)&agg[(size_t)d * 256 + lane * 4] = p;
}

// ---------------------------------------------------------------------------
// K7: dense bf16 MFMA GEMM + GRU gates.
// NEW (this round): SINGLE-buffer LDS (24.6 KB) -> 6 blocks/CU instead of 3.
// Counters (MfmaUtil 3.7%, VALUBusy 10%, HBM 7%) say the kernel is
// latency-bound with idle pipes: it needs more independent blocks, not
// intra-block prefetch overlap. Weight slabs are L2-resident (196 KB total),
// so the exposed stage latency per cb is short and is hidden by the doubled
// block-level TLP; 782 blocks now fit in ONE generation (capacity 1536).
// XOR-swizzle (16B slot ^= row&15) on both global source and LDS read is
// unchanged; hv/bias hoist (R9, -5 us) unchanged.
#define GLOAD_LDS16(gp, lp)                                                   \
    __builtin_amdgcn_global_load_lds(                                         \
        (const __attribute__((address_space(1))) void*)(gp),                  \
        (__attribute__((address_space(3))) void*)(lp), 16, 0, 0)

__global__ __launch_bounds__(256, 6) void gemm_gates_kernel(
    const short* __restrict__ agg, const float* __restrict__ hx,
    const short* __restrict__ Wbf,
    const float* __restrict__ bi, const float* __restrict__ bh,
    float* __restrict__ out, int N) {
    __shared__ short wlds[12288];               // 24.6 KB single buffer
    const int tid = threadIdx.x;
    const int wv = tid >> 6, lane = tid & 63;
    const int l15 = lane & 15, quad = lane >> 4;
    const int rowBase = (blockIdx.x * 4 + wv) * 16;
    const bool active = rowBase < N;   // N % 16 == 0: active waves fully valid

    // A-fragments preloaded to registers BEFORE any out store (agg aliases
    // out; each wave reads/writes only its own 16 rows -> no hazard).
    int arow = active ? rowBase + l15 : 0;
    const short* aPtr = agg + (size_t)arow * 256;
    bf16x8 aLo[4], aHi[4];
    #pragma unroll
    for (int kst = 0; kst < 4; ++kst) {
        aLo[kst] = *(const bf16x8*)&aPtr[kst * 32 + quad * 8];
        aHi[kst] = *(const bf16x8*)&aPtr[128 + kst * 32 + quad * 8];
    }

    for (int cb = 0; cb < 8; ++cb) {
        // Stage this cb's slab (each wave copies its own 6144 B chunk).
        {
            const char* gs = (const char*)(Wbf + (size_t)cb * 12288);
            #pragma unroll
            for (int i = 0; i < 6; ++i) {
                int ldsByte = wv * 6144 + i * 1024 + lane * 16;
                int gByte = ldsByte ^ (((ldsByte >> 8) & 15) << 4);   // slot ^= row&15
                GLOAD_LDS16(gs + gByte, (char*)wlds + wv * 6144 + i * 1024);
            }
        }
        // Hoisted epilogue operands: independent global loads issued before
        // the barrier so they overlap the staging drain.
        int ocol = cb * 16 + l15;
        float hv[4];
        float bir = 0.f, biz = 0.f, bin = 0.f, bhr = 0.f, bhz = 0.f, bhn = 0.f;
        if (active) {
            #pragma unroll
            for (int reg = 0; reg < 4; ++reg)
                hv[reg] = hx[(size_t)(rowBase + quad * 4 + reg) * DIM + ocol];
            bir = bi[ocol]; biz = bi[128 + ocol]; bin = bi[256 + ocol];
            bhr = bh[ocol]; bhz = bh[128 + ocol]; bhn = bh[256 + ocol];
        }
        __syncthreads();   // compiler drains vmcnt(0) -> slab visible

        if (active) {
            f32x4v acc[6];
            #pragma unroll
            for (int g = 0; g < 6; ++g) acc[g] = (f32x4v){0.f, 0.f, 0.f, 0.f};
            const char* slab = (const char*)wlds;
            #pragma unroll
            for (int kst = 0; kst < 4; ++kst) {
                const int co = (((kst * 4 + quad) ^ l15) << 4);   // swizzled col
                #pragma unroll
                for (int g = 0; g < 3; ++g) {
                    bf16x8 bI = *(const bf16x8*)(slab + g * 4096 + l15 * 256 + co);
                    acc[g] = __builtin_amdgcn_mfma_f32_16x16x32_bf16(
                        aLo[kst], bI, acc[g], 0, 0, 0);
                    bf16x8 bH = *(const bf16x8*)(slab + (g + 3) * 4096 + l15 * 256 + co);
                    acc[g + 3] = __builtin_amdgcn_mfma_f32_16x16x32_bf16(
                        aHi[kst], bH, acc[g + 3], 0, 0, 0);
                }
            }
            #pragma unroll
            for (int reg = 0; reg < 4; ++reg) {
                int row = rowBase + quad * 4 + reg;
                float ir = acc[0][reg] + bir, iz = acc[1][reg] + biz, in_ = acc[2][reg] + bin;
                float hr = acc[3][reg] + bhr, hz = acc[4][reg] + bhz, hn = acc[5][reg] + bhn;
                float rg = 1.0f / (1.0f + __expf(-(ir + hr)));
                float zg = 1.0f / (1.0f + __expf(-(iz + hz)));
                float ng = tanhf(in_ + rg * hn);
                out[(size_t)row * DIM + ocol] = (1.0f - zg) * ng + zg * hv[reg];
            }
        }
        if (cb != 7) __syncthreads();   // all waves done reading before overwrite
    }
}

// ---------------------------------------------------------------------------
extern "C" void kernel_launch(void* const* d_in, const int* in_sizes, int n_in,
                              void* d_out, int out_size, void* d_ws, size_t ws_size,
                              hipStream_t stream) {
    const float* feat = (const float*)d_in[0];
    const float* hx   = (const float*)d_in[1];
    const float* Wi   = (const float*)d_in[2];
    const float* bi   = (const float*)d_in[3];
    const float* Wh   = (const float*)d_in[4];
    const float* bh   = (const float*)d_in[5];
    const int* src    = (const int*)d_in[6];
    const int* dst    = (const int*)d_in[7];
    float* out        = (float*)d_out;

    int N = in_sizes[0] / DIM;   // 50000
    int E = in_sizes[6];         // 800000
    int Npad = (N + 1) & ~1;     // even stride for u16-pair word copies
    int chunk = (E + NCH - 1) / NCH;     // 25000 (< 65536 -> u16 counters)
    int NB    = (N + 255) / 256;         // 196 (<= 256 for the LDS scan)

    unsigned short* partI = (unsigned short*)d_ws;            // NCH*Npad u16
    unsigned short* partO = partI + (size_t)NCH * Npad;       // NCH*Npad u16
    int* csrOffC   = (int*)(partO + (size_t)NCH * Npad);      // NCH*N
    int* csrOff    = csrOffC + (size_t)NCH * N;               // N+1
    int* srcSorted = csrOff + N + 1;                          // E
    unsigned short* rank = (unsigned short*)(srcSorted + E);  // E u16
    int* bsum      = (int*)(rank + ((E + 1) & ~1));           // 256
    float* normIf  = (float*)(bsum + 256);                    // N
    float* normOf  = normIf + N;                              // N
    size_t iend = (size_t)(normOf + N - (float*)d_ws);
    size_t wofs = (iend * 4 + 15) & ~(size_t)15;
    short* Wbf = (short*)((char*)d_ws + wofs);                // 98304 bf16
    size_t fofs = (wofs + 98304 * 2 + 15) & ~(size_t)15;
    short* fh = (short*)((char*)d_ws + fofs);                 // N*256 bf16
    // total ws: ~45 MB (proven-safe budget: 51.6 MB)
    short* agg = (short*)d_out;  // bf16 agg aliased over d_out

    k_hist<<<2 * NCH, 1024, 0, stream>>>(src, dst, partO, partI, rank,
                                         N, Npad, E, chunk);
    k_bsum<<<NB, 256, 0, stream>>>(partI, bsum, N, Npad);
    k_off<<<NB, 256, 0, stream>>>(partI, partO, bsum, csrOffC, csrOff,
                                  normIf, normOf, N, Npad, NB);
    k_xcw<<<(N * 64 + 98304 + 255) / 256, 256, 0, stream>>>(
        feat, hx, Wi, Wh, normOf, Wbf, fh, N);
    k_fill<<<(E + 255) / 256, 256, 0, stream>>>(
        src, dst, rank, csrOffC, srcSorted, N, E, chunk);

    gather_kernel<<<(N + 3) / 4, 256, 0, stream>>>(
        fh, csrOff, srcSorted, normIf, agg, N);
    gemm_gates_kernel<<<(N + 63) / 64, 256, 0, stream>>>(
        agg, hx, Wbf, bi, bh, out, N);
}

// Round 13
// 246.057 us; speedup vs baseline: 1.1556x; 1.1556x over previous
//
#include <hip/hip_runtime.h>
#include <math.h>

#define DIM 128
#define NCH 32          // edge chunks; per-chunk per-node count < 65536 -> u16
#define NMAXW 25024     // LDS histogram words (covers N <= 50048)

typedef float f32x4v __attribute__((ext_vector_type(4)));
typedef short bf16x8 __attribute__((ext_vector_type(8)));

static __device__ __forceinline__ short f2bf(float f) {
    unsigned u = __float_as_uint(f);
    unsigned r = (u + 0x7fffu + ((u >> 16) & 1u)) >> 16;   // RNE
    return (short)r;
}
static __device__ __forceinline__ float bf2f(unsigned short s) {
    return __uint_as_float(((unsigned)s) << 16);
}

// ---------------------------------------------------------------------------
// K1: ONE-PASS full-N LDS histogram per edge chunk (u16 packed counters).
// Per-chunk counts < 65536 -> full-N u16 histogram = 100 KB LDS. Packed u16
// atomics on u32 words (halves can't carry: each half < 2^16). Blocks
// [0,NCH): dst histogram + rank (dense coalesced u16 write); [NCH,2NCH):
// src histogram. Edge reads: 6.4 MB, once.
// Kept standalone: R11's merged wconv/bsum variant regressed ~13 us (every
// block inherited the 100 KB static LDS; hist critical path grew).
__global__ __launch_bounds__(1024) void k_hist(const int* __restrict__ src,
                                               const int* __restrict__ dst,
                                               unsigned short* __restrict__ partO,
                                               unsigned short* __restrict__ partI,
                                               unsigned short* __restrict__ rank,
                                               int N, int Npad, int E, int chunk) {
    __shared__ unsigned int h[NMAXW];
    int t = threadIdx.x;
    int isI = blockIdx.x < NCH;
    int c = isI ? blockIdx.x : blockIdx.x - NCH;
    int NW = (N + 1) >> 1;
    for (int i = t; i < NW; i += 1024) h[i] = 0;
    __syncthreads();
    int e0 = c * chunk, e1 = min(e0 + chunk, E);
    if (isI) {
        for (int e = e0 + t; e < e1; e += 1024) {
            int d = dst[e];
            unsigned sh = (d & 1) * 16;
            unsigned old = atomicAdd(&h[d >> 1], 1u << sh);   // LDS atomic
            rank[e] = (unsigned short)((old >> sh) & 0xffffu);
        }
    } else {
        for (int e = e0 + t; e < e1; e += 1024) {
            int s = src[e];
            atomicAdd(&h[s >> 1], 1u << ((s & 1) * 16));
        }
    }
    __syncthreads();
    unsigned int* p = (unsigned int*)((isI ? partI : partO) + (size_t)c * Npad);
    for (int i = t; i < NW; i += 1024) p[i] = h[i];   // u16 pair per word
}

// K2: per-256-node block sums of degI (over the NCH chunk partials).
__global__ __launch_bounds__(256) void k_bsum(const unsigned short* __restrict__ partI,
                                              int* __restrict__ bsum, int N, int Npad) {
    __shared__ int red[4];
    int b = blockIdx.x, t = threadIdx.x;
    int n = b * 256 + t;
    int s = 0;
    if (n < N) {
        #pragma unroll
        for (int c = 0; c < NCH; ++c) s += partI[(size_t)c * Npad + n];
    }
    for (int off = 32; off; off >>= 1) s += __shfl_down(s, off);
    if ((t & 63) == 0) red[t >> 6] = s;
    __syncthreads();
    if (t == 0) bsum[b] = red[0] + red[1] + red[2] + red[3];
}

// K3: exclusive scan -> csrOff + per-chunk bases csrOffC + norm factors.
// One node per thread, NB <= 256 blocks, LDS Hillis-Steele scans.
__global__ __launch_bounds__(256) void k_off(const unsigned short* __restrict__ partI,
                                             const unsigned short* __restrict__ partO,
                                             const int* __restrict__ bsum,
                                             int* __restrict__ csrOffC,
                                             int* __restrict__ csrOff,
                                             float* __restrict__ normIf,
                                             float* __restrict__ normOf,
                                             int N, int Npad, int NB) {
    __shared__ int sp[256];
    __shared__ int sbase;
    int b = blockIdx.x, t = threadIdx.x;
    int own = (t < NB) ? bsum[t] : 0;
    sp[t] = own;
    __syncthreads();
    for (int off = 1; off < 256; off <<= 1) {
        int u = (t >= off) ? sp[t - off] : 0;
        __syncthreads();
        sp[t] += u;
        __syncthreads();
    }
    if (t == b) sbase = sp[t] - own;
    if (b == 0 && t == NB - 1) csrOff[N] = sp[t];
    __syncthreads();
    int n = b * 256 + t;
    int cv[NCH];
    int tI = 0, tO = 0;
    if (n < N) {
        #pragma unroll
        for (int c = 0; c < NCH; ++c) {
            cv[c] = partI[(size_t)c * Npad + n];
            tI += cv[c];
            tO += partO[(size_t)c * Npad + n];
        }
    }
    sp[t] = tI;
    __syncthreads();
    for (int off = 1; off < 256; off <<= 1) {
        int u = (t >= off) ? sp[t - off] : 0;
        __syncthreads();
        sp[t] += u;
        __syncthreads();
    }
    int o = sbase + sp[t] - tI;
    if (n < N) {
        csrOff[n] = o;
        normIf[n] = rsqrtf(fmaxf((float)tI, 1.0f));
        normOf[n] = rsqrtf(fmaxf((float)tO, 1.0f));
        int base = o;
        #pragma unroll
        for (int c = 0; c < NCH; ++c) {
            csrOffC[(size_t)c * N + n] = base;
            base += cv[c];
        }
    }
}

// K4: merged pre-scaled bf16 feat/hx + bf16 weight convert.
__global__ __launch_bounds__(256) void k_xcw(const float* __restrict__ feat,
                                             const float* __restrict__ hx,
                                             const float* __restrict__ Wi,
                                             const float* __restrict__ Wh,
                                             const float* __restrict__ normOf,
                                             short* __restrict__ Wbf,
                                             short* __restrict__ fh, int N) {
    int i = blockIdx.x * 256 + threadIdx.x;
    int T1 = N * 64;
    if (i < T1) {
        int n = i >> 6, q = i & 63;
        float ns = normOf[n];
        const float* spp = (q < 32) ? &feat[(size_t)n * 128 + q * 4]
                                    : &hx[(size_t)n * 128 + (q - 32) * 4];
        float4 v = *(const float4*)spp;
        short4 p;
        p.x = f2bf(v.x * ns); p.y = f2bf(v.y * ns);
        p.z = f2bf(v.z * ns); p.w = f2bf(v.w * ns);
        *(short4*)&fh[(size_t)n * 256 + q * 4] = p;   // q*4 == 128+(q-32)*4
    } else {
        int w = i - T1;
        if (w < 98304) {
            int k = w & 127, n = (w >> 7) & 15, r = w >> 11;
            int gm = r % 6, cb = r / 6;
            const float* Wsrc = (gm < 3) ? Wi : Wh;
            int g = gm % 3;
            Wbf[w] = f2bf(Wsrc[k * 384 + g * 128 + cb * 16 + n]);
        }
    }
}

// K5: atomic-free counting-sort fill (pos = csrOffC[e/chunk][dst] + rank).
__global__ __launch_bounds__(256) void k_fill(const int* __restrict__ src,
                                              const int* __restrict__ dst,
                                              const unsigned short* __restrict__ rank,
                                              const int* __restrict__ csrOffC,
                                              int* __restrict__ srcSorted,
                                              int N, int E, int chunk) {
    int e = blockIdx.x * 256 + threadIdx.x;
    if (e < E) {
        int c = e / chunk;
        int pos = csrOffC[(size_t)c * N + dst[e]] + (int)rank[e];
        srcSorted[pos] = src[e];
    }
}

// ---------------------------------------------------------------------------
// K6: gather-aggregate. R1 form, FROZEN: one wave per dst node, 12500 blocks,
// wave-uniform scalar index loads, 8 B/lane row reads, 28 VGPR. Five
// structural variants (half-wave split R2, explicit batch R3, shfl-broadcast
// R7, grid-stride R10) were all neutral or regressed — high TLP plus this
// exact chain is the measured floor (~65 us, 214 MB compulsory L2-miss).
__global__ __launch_bounds__(256) void gather_kernel(
    const short* __restrict__ fh, const int* __restrict__ csrOff,
    const int* __restrict__ srcSorted, const float* __restrict__ normIf,
    short* __restrict__ agg, int N) {
    int wv = threadIdx.x >> 6, lane = threadIdx.x & 63;
    int d = blockIdx.x * 4 + wv;
    if (d >= N) return;
    const ushort4* fh4 = (const ushort4*)fh;
    int beg = csrOff[d], end = csrOff[d + 1];
    float4 acc = make_float4(0.f, 0.f, 0.f, 0.f);
    #pragma unroll 8
    for (int e = beg; e < end; ++e) {
        int s = srcSorted[e];                     // wave-uniform scalar load
        ushort4 v = fh4[(size_t)s * 64 + lane];   // 8B/lane, 512B/wave
        acc.x += bf2f(v.x); acc.y += bf2f(v.y);
        acc.z += bf2f(v.z); acc.w += bf2f(v.w);
    }
    float nd = normIf[d];
    short4 p;
    p.x = f2bf(acc.x * nd); p.y = f2bf(acc.y * nd);
    p.z = f2bf(acc.z * nd); p.w = f2bf(acc.w * nd);
    *(short4*)&agg[(size_t)d * 256 + lane * 4] = p;
}

// ---------------------------------------------------------------------------
// K7: dense bf16 MFMA GEMM + GRU gates. R9 form, FROZEN: double-buffered LDS
// (2 x 24.6 KB, 3 blocks/CU) with global_load_lds width=16 prefetch crossing
// one barrier per cb; XOR-swizzle (16B slot ^= row&15) on both global source
// and LDS read; hv/bias hoisted above the MFMA cluster (R9: -5 us).
// R12's single-buffer/6-blocks variant regressed to 75 us (FETCH 26->132 MB:
// barrier-chopped phases destroyed L2 residency). Keep this shape.
#define GLOAD_LDS16(gp, lp)                                                   \
    __builtin_amdgcn_global_load_lds(                                         \
        (const __attribute__((address_space(1))) void*)(gp),                  \
        (__attribute__((address_space(3))) void*)(lp), 16, 0, 0)

__global__ __launch_bounds__(256, 3) void gemm_gates_kernel(
    const short* __restrict__ agg, const float* __restrict__ hx,
    const short* __restrict__ Wbf,
    const float* __restrict__ bi, const float* __restrict__ bh,
    float* __restrict__ out, int N) {
    __shared__ short wlds[2][12288];            // 2 x 24.6 KB double buffer
    const int tid = threadIdx.x;
    const int wv = tid >> 6, lane = tid & 63;
    const int l15 = lane & 15, quad = lane >> 4;
    const int rowBase = (blockIdx.x * 4 + wv) * 16;
    const bool active = rowBase < N;   // N % 16 == 0: active waves fully valid

    // A-fragments preloaded to registers BEFORE any out store (agg aliases
    // out; each wave reads/writes only its own 16 rows -> no hazard).
    int arow = active ? rowBase + l15 : 0;
    const short* aPtr = agg + (size_t)arow * 256;
    bf16x8 aLo[4], aHi[4];
    #pragma unroll
    for (int kst = 0; kst < 4; ++kst) {
        aLo[kst] = *(const bf16x8*)&aPtr[kst * 32 + quad * 8];
        aHi[kst] = *(const bf16x8*)&aPtr[128 + kst * 32 + quad * 8];
    }

    // Prologue: stage cb=0 slab (each wave copies its own 6144 B chunk).
    {
        const char* gs = (const char*)Wbf;
        #pragma unroll
        for (int i = 0; i < 6; ++i) {
            int ldsByte = wv * 6144 + i * 1024 + lane * 16;
            int gByte = ldsByte ^ (((ldsByte >> 8) & 15) << 4);   // slot ^= row&15
            GLOAD_LDS16(gs + gByte, (char*)&wlds[0][0] + wv * 6144 + i * 1024);
        }
    }
    __syncthreads();   // compiler drains vmcnt(0) before s_barrier

    for (int cb = 0; cb < 8; ++cb) {
        const int buf = cb & 1;
        if (cb < 7) {   // async prefetch next slab into the other buffer
            const char* gs = (const char*)(Wbf + (size_t)(cb + 1) * 12288);
            #pragma unroll
            for (int i = 0; i < 6; ++i) {
                int ldsByte = wv * 6144 + i * 1024 + lane * 16;
                int gByte = ldsByte ^ (((ldsByte >> 8) & 15) << 4);
                GLOAD_LDS16(gs + gByte,
                            (char*)&wlds[buf ^ 1][0] + wv * 6144 + i * 1024);
            }
        }
        if (active) {
            // Hoisted epilogue operands: issue loads before the MFMA cluster
            // so their latency hides under the matrix work.
            int ocol = cb * 16 + l15;
            float hv[4];
            #pragma unroll
            for (int reg = 0; reg < 4; ++reg)
                hv[reg] = hx[(size_t)(rowBase + quad * 4 + reg) * DIM + ocol];
            float bir = bi[ocol], biz = bi[128 + ocol], bin = bi[256 + ocol];
            float bhr = bh[ocol], bhz = bh[128 + ocol], bhn = bh[256 + ocol];

            f32x4v acc[6];
            #pragma unroll
            for (int g = 0; g < 6; ++g) acc[g] = (f32x4v){0.f, 0.f, 0.f, 0.f};
            const char* slab = (const char*)&wlds[buf][0];
            #pragma unroll
            for (int kst = 0; kst < 4; ++kst) {
                const int co = (((kst * 4 + quad) ^ l15) << 4);   // swizzled col
                #pragma unroll
                for (int g = 0; g < 3; ++g) {
                    bf16x8 bI = *(const bf16x8*)(slab + g * 4096 + l15 * 256 + co);
                    acc[g] = __builtin_amdgcn_mfma_f32_16x16x32_bf16(
                        aLo[kst], bI, acc[g], 0, 0, 0);
                    bf16x8 bH = *(const bf16x8*)(slab + (g + 3) * 4096 + l15 * 256 + co);
                    acc[g + 3] = __builtin_amdgcn_mfma_f32_16x16x32_bf16(
                        aHi[kst], bH, acc[g + 3], 0, 0, 0);
                }
            }
            #pragma unroll
            for (int reg = 0; reg < 4; ++reg) {
                int row = rowBase + quad * 4 + reg;
                float ir = acc[0][reg] + bir, iz = acc[1][reg] + biz, in_ = acc[2][reg] + bin;
                float hr = acc[3][reg] + bhr, hz = acc[4][reg] + bhz, hn = acc[5][reg] + bhn;
                float rg = 1.0f / (1.0f + __expf(-(ir + hr)));
                float zg = 1.0f / (1.0f + __expf(-(iz + hz)));
                float ng = tanhf(in_ + rg * hn);
                out[(size_t)row * DIM + ocol] = (1.0f - zg) * ng + zg * hv[reg];
            }
        }
        __syncthreads();   // drains this iter's prefetch; protects buf reuse
    }
}

// ---------------------------------------------------------------------------
extern "C" void kernel_launch(void* const* d_in, const int* in_sizes, int n_in,
                              void* d_out, int out_size, void* d_ws, size_t ws_size,
                              hipStream_t stream) {
    const float* feat = (const float*)d_in[0];
    const float* hx   = (const float*)d_in[1];
    const float* Wi   = (const float*)d_in[2];
    const float* bi   = (const float*)d_in[3];
    const float* Wh   = (const float*)d_in[4];
    const float* bh   = (const float*)d_in[5];
    const int* src    = (const int*)d_in[6];
    const int* dst    = (const int*)d_in[7];
    float* out        = (float*)d_out;

    int N = in_sizes[0] / DIM;   // 50000
    int E = in_sizes[6];         // 800000
    int Npad = (N + 1) & ~1;     // even stride for u16-pair word copies
    int chunk = (E + NCH - 1) / NCH;     // 25000 (< 65536 -> u16 counters)
    int NB    = (N + 255) / 256;         // 196 (<= 256 for the LDS scan)

    unsigned short* partI = (unsigned short*)d_ws;            // NCH*Npad u16
    unsigned short* partO = partI + (size_t)NCH * Npad;       // NCH*Npad u16
    int* csrOffC   = (int*)(partO + (size_t)NCH * Npad);      // NCH*N
    int* csrOff    = csrOffC + (size_t)NCH * N;               // N+1
    int* srcSorted = csrOff + N + 1;                          // E
    unsigned short* rank = (unsigned short*)(srcSorted + E);  // E u16
    int* bsum      = (int*)(rank + ((E + 1) & ~1));           // 256
    float* normIf  = (float*)(bsum + 256);                    // N
    float* normOf  = normIf + N;                              // N
    size_t iend = (size_t)(normOf + N - (float*)d_ws);
    size_t wofs = (iend * 4 + 15) & ~(size_t)15;
    short* Wbf = (short*)((char*)d_ws + wofs);                // 98304 bf16
    size_t fofs = (wofs + 98304 * 2 + 15) & ~(size_t)15;
    short* fh = (short*)((char*)d_ws + fofs);                 // N*256 bf16
    // total ws: ~45 MB (proven-safe budget: 51.6 MB)
    short* agg = (short*)d_out;  // bf16 agg aliased over d_out

    k_hist<<<2 * NCH, 1024, 0, stream>>>(src, dst, partO, partI, rank,
                                         N, Npad, E, chunk);
    k_bsum<<<NB, 256, 0, stream>>>(partI, bsum, N, Npad);
    k_off<<<NB, 256, 0, stream>>>(partI, partO, bsum, csrOffC, csrOff,
                                  normIf, normOf, N, Npad, NB);
    k_xcw<<<(N * 64 + 98304 + 255) / 256, 256, 0, stream>>>(
        feat, hx, Wi, Wh, normOf, Wbf, fh, N);
    k_fill<<<(E + 255) / 256, 256, 0, stream>>>(
        src, dst, rank, csrOffC, srcSorted, N, E, chunk);

    gather_kernel<<<(N + 3) / 4, 256, 0, stream>>>(
        fh, csrOff, srcSorted, normIf, agg, N);
    gemm_gates_kernel<<<(N + 63) / 64, 256, 0, stream>>>(
        agg, hx, Wbf, bi, bh, out, N);
}

// Round 14
// 241.898 us; speedup vs baseline: 1.1754x; 1.0172x over previous
//
#include <hip/hip_runtime.h>
#include <math.h>

#define DIM 128
#define NCH 32          // edge chunks; per-chunk per-node count < 65536 -> u16
#define NMAXW 25024     // LDS histogram words (covers N <= 50048)

typedef float f32x4v __attribute__((ext_vector_type(4)));
typedef short bf16x8 __attribute__((ext_vector_type(8)));

static __device__ __forceinline__ short f2bf(float f) {
    unsigned u = __float_as_uint(f);
    unsigned r = (u + 0x7fffu + ((u >> 16) & 1u)) >> 16;   // RNE
    return (short)r;
}
static __device__ __forceinline__ float bf2f(unsigned short s) {
    return __uint_as_float(((unsigned)s) << 16);
}

// ---------------------------------------------------------------------------
// K1: ONE-PASS full-N LDS histogram per edge chunk (u16 packed counters).
// Per-chunk counts < 65536 -> full-N u16 histogram = 100 KB LDS. Packed u16
// atomics on u32 words (halves can't carry: each half < 2^16). Blocks
// [0,NCH): dst histogram + rank (dense coalesced u16 write); [NCH,2NCH):
// src histogram. Edge reads: 6.4 MB, once.
// Kept standalone: R11's merged wconv/bsum variant regressed ~13 us (every
// block inherited the 100 KB static LDS; hist critical path grew).
__global__ __launch_bounds__(1024) void k_hist(const int* __restrict__ src,
                                               const int* __restrict__ dst,
                                               unsigned short* __restrict__ partO,
                                               unsigned short* __restrict__ partI,
                                               unsigned short* __restrict__ rank,
                                               int N, int Npad, int E, int chunk) {
    __shared__ unsigned int h[NMAXW];
    int t = threadIdx.x;
    int isI = blockIdx.x < NCH;
    int c = isI ? blockIdx.x : blockIdx.x - NCH;
    int NW = (N + 1) >> 1;
    for (int i = t; i < NW; i += 1024) h[i] = 0;
    __syncthreads();
    int e0 = c * chunk, e1 = min(e0 + chunk, E);
    if (isI) {
        for (int e = e0 + t; e < e1; e += 1024) {
            int d = dst[e];
            unsigned sh = (d & 1) * 16;
            unsigned old = atomicAdd(&h[d >> 1], 1u << sh);   // LDS atomic
            rank[e] = (unsigned short)((old >> sh) & 0xffffu);
        }
    } else {
        for (int e = e0 + t; e < e1; e += 1024) {
            int s = src[e];
            atomicAdd(&h[s >> 1], 1u << ((s & 1) * 16));
        }
    }
    __syncthreads();
    unsigned int* p = (unsigned int*)((isI ? partI : partO) + (size_t)c * Npad);
    for (int i = t; i < NW; i += 1024) p[i] = h[i];   // u16 pair per word
}

// K2: per-256-node block sums of degI (over the NCH chunk partials).
__global__ __launch_bounds__(256) void k_bsum(const unsigned short* __restrict__ partI,
                                              int* __restrict__ bsum, int N, int Npad) {
    __shared__ int red[4];
    int b = blockIdx.x, t = threadIdx.x;
    int n = b * 256 + t;
    int s = 0;
    if (n < N) {
        #pragma unroll
        for (int c = 0; c < NCH; ++c) s += partI[(size_t)c * Npad + n];
    }
    for (int off = 32; off; off >>= 1) s += __shfl_down(s, off);
    if ((t & 63) == 0) red[t >> 6] = s;
    __syncthreads();
    if (t == 0) bsum[b] = red[0] + red[1] + red[2] + red[3];
}

// K3: exclusive scan -> csrOff + per-chunk bases csrOffC + norm factors.
// One node per thread, NB <= 256 blocks, LDS Hillis-Steele scans.
__global__ __launch_bounds__(256) void k_off(const unsigned short* __restrict__ partI,
                                             const unsigned short* __restrict__ partO,
                                             const int* __restrict__ bsum,
                                             int* __restrict__ csrOffC,
                                             int* __restrict__ csrOff,
                                             float* __restrict__ normIf,
                                             float* __restrict__ normOf,
                                             int N, int Npad, int NB) {
    __shared__ int sp[256];
    __shared__ int sbase;
    int b = blockIdx.x, t = threadIdx.x;
    int own = (t < NB) ? bsum[t] : 0;
    sp[t] = own;
    __syncthreads();
    for (int off = 1; off < 256; off <<= 1) {
        int u = (t >= off) ? sp[t - off] : 0;
        __syncthreads();
        sp[t] += u;
        __syncthreads();
    }
    if (t == b) sbase = sp[t] - own;
    if (b == 0 && t == NB - 1) csrOff[N] = sp[t];
    __syncthreads();
    int n = b * 256 + t;
    int cv[NCH];
    int tI = 0, tO = 0;
    if (n < N) {
        #pragma unroll
        for (int c = 0; c < NCH; ++c) {
            cv[c] = partI[(size_t)c * Npad + n];
            tI += cv[c];
            tO += partO[(size_t)c * Npad + n];
        }
    }
    sp[t] = tI;
    __syncthreads();
    for (int off = 1; off < 256; off <<= 1) {
        int u = (t >= off) ? sp[t - off] : 0;
        __syncthreads();
        sp[t] += u;
        __syncthreads();
    }
    int o = sbase + sp[t] - tI;
    if (n < N) {
        csrOff[n] = o;
        normIf[n] = rsqrtf(fmaxf((float)tI, 1.0f));
        normOf[n] = rsqrtf(fmaxf((float)tO, 1.0f));
        int base = o;
        #pragma unroll
        for (int c = 0; c < NCH; ++c) {
            csrOffC[(size_t)c * N + n] = base;
            base += cv[c];
        }
    }
}

// K4: merged pre-scaled bf16 feat/hx + bf16 weight convert + counting-sort
// fill. Re-merged (R10 accounting: the merged form was ~3 us faster than the
// R9 split — one less launch gap; discarded in R10 only because that round's
// gather change regressed).
__global__ __launch_bounds__(256) void k_xcw(const float* __restrict__ feat,
                                             const float* __restrict__ hx,
                                             const float* __restrict__ Wi,
                                             const float* __restrict__ Wh,
                                             const float* __restrict__ normOf,
                                             short* __restrict__ Wbf,
                                             short* __restrict__ fh,
                                             const int* __restrict__ src,
                                             const int* __restrict__ dst,
                                             const unsigned short* __restrict__ rank,
                                             const int* __restrict__ csrOffC,
                                             int* __restrict__ srcSorted,
                                             int N, int E, int chunk) {
    int i = blockIdx.x * 256 + threadIdx.x;
    int T1 = N * 64;
    int T2 = T1 + 98304;
    if (i < T1) {
        int n = i >> 6, q = i & 63;
        float ns = normOf[n];
        const float* spp = (q < 32) ? &feat[(size_t)n * 128 + q * 4]
                                    : &hx[(size_t)n * 128 + (q - 32) * 4];
        float4 v = *(const float4*)spp;
        short4 p;
        p.x = f2bf(v.x * ns); p.y = f2bf(v.y * ns);
        p.z = f2bf(v.z * ns); p.w = f2bf(v.w * ns);
        *(short4*)&fh[(size_t)n * 256 + q * 4] = p;   // q*4 == 128+(q-32)*4
    } else if (i < T2) {
        int w = i - T1;
        int k = w & 127, n = (w >> 7) & 15, r = w >> 11;
        int gm = r % 6, cb = r / 6;
        const float* Wsrc = (gm < 3) ? Wi : Wh;
        int g = gm % 3;
        Wbf[w] = f2bf(Wsrc[k * 384 + g * 128 + cb * 16 + n]);
    } else {
        int e = i - T2;
        if (e < E) {
            int c = e / chunk;
            int pos = csrOffC[(size_t)c * N + dst[e]] + (int)rank[e];
            srcSorted[pos] = src[e];
        }
    }
}

// ---------------------------------------------------------------------------
// K6: gather-aggregate. R1 form, FROZEN: one wave per dst node, 12500 blocks,
// wave-uniform scalar index loads, 8 B/lane row reads, 28 VGPR. Five
// structural variants (half-wave split R2, explicit batch R3, shfl-broadcast
// R7, grid-stride R10) were all neutral or regressed — high TLP plus this
// exact chain is the measured floor (~65 us, 214 MB compulsory L2-miss).
__global__ __launch_bounds__(256) void gather_kernel(
    const short* __restrict__ fh, const int* __restrict__ csrOff,
    const int* __restrict__ srcSorted, const float* __restrict__ normIf,
    short* __restrict__ agg, int N) {
    int wv = threadIdx.x >> 6, lane = threadIdx.x & 63;
    int d = blockIdx.x * 4 + wv;
    if (d >= N) return;
    const ushort4* fh4 = (const ushort4*)fh;
    int beg = csrOff[d], end = csrOff[d + 1];
    float4 acc = make_float4(0.f, 0.f, 0.f, 0.f);
    #pragma unroll 8
    for (int e = beg; e < end; ++e) {
        int s = srcSorted[e];                     // wave-uniform scalar load
        ushort4 v = fh4[(size_t)s * 64 + lane];   // 8B/lane, 512B/wave
        acc.x += bf2f(v.x); acc.y += bf2f(v.y);
        acc.z += bf2f(v.z); acc.w += bf2f(v.w);
    }
    float nd = normIf[d];
    short4 p;
    p.x = f2bf(acc.x * nd); p.y = f2bf(acc.y * nd);
    p.z = f2bf(acc.z * nd); p.w = f2bf(acc.w * nd);
    *(short4*)&agg[(size_t)d * 256 + lane * 4] = p;
}

// ---------------------------------------------------------------------------
// K7: dense bf16 MFMA GEMM + GRU gates. R9 form, FROZEN: double-buffered LDS
// (2 x 24.6 KB, 3 blocks/CU) with global_load_lds width=16 prefetch crossing
// one barrier per cb; XOR-swizzle (16B slot ^= row&15) on both global source
// and LDS read; hv/bias hoisted above the MFMA cluster (R9: -5 us).
// R12's single-buffer/6-blocks variant regressed to 75 us (FETCH 26->132 MB:
// barrier-chopped phases destroyed L2 residency). Keep this shape.
#define GLOAD_LDS16(gp, lp)                                                   \
    __builtin_amdgcn_global_load_lds(                                         \
        (const __attribute__((address_space(1))) void*)(gp),                  \
        (__attribute__((address_space(3))) void*)(lp), 16, 0, 0)

__global__ __launch_bounds__(256, 3) void gemm_gates_kernel(
    const short* __restrict__ agg, const float* __restrict__ hx,
    const short* __restrict__ Wbf,
    const float* __restrict__ bi, const float* __restrict__ bh,
    float* __restrict__ out, int N) {
    __shared__ short wlds[2][12288];            // 2 x 24.6 KB double buffer
    const int tid = threadIdx.x;
    const int wv = tid >> 6, lane = tid & 63;
    const int l15 = lane & 15, quad = lane >> 4;
    const int rowBase = (blockIdx.x * 4 + wv) * 16;
    const bool active = rowBase < N;   // N % 16 == 0: active waves fully valid

    // A-fragments preloaded to registers BEFORE any out store (agg aliases
    // out; each wave reads/writes only its own 16 rows -> no hazard).
    int arow = active ? rowBase + l15 : 0;
    const short* aPtr = agg + (size_t)arow * 256;
    bf16x8 aLo[4], aHi[4];
    #pragma unroll
    for (int kst = 0; kst < 4; ++kst) {
        aLo[kst] = *(const bf16x8*)&aPtr[kst * 32 + quad * 8];
        aHi[kst] = *(const bf16x8*)&aPtr[128 + kst * 32 + quad * 8];
    }

    // Prologue: stage cb=0 slab (each wave copies its own 6144 B chunk).
    {
        const char* gs = (const char*)Wbf;
        #pragma unroll
        for (int i = 0; i < 6; ++i) {
            int ldsByte = wv * 6144 + i * 1024 + lane * 16;
            int gByte = ldsByte ^ (((ldsByte >> 8) & 15) << 4);   // slot ^= row&15
            GLOAD_LDS16(gs + gByte, (char*)&wlds[0][0] + wv * 6144 + i * 1024);
        }
    }
    __syncthreads();   // compiler drains vmcnt(0) before s_barrier

    for (int cb = 0; cb < 8; ++cb) {
        const int buf = cb & 1;
        if (cb < 7) {   // async prefetch next slab into the other buffer
            const char* gs = (const char*)(Wbf + (size_t)(cb + 1) * 12288);
            #pragma unroll
            for (int i = 0; i < 6; ++i) {
                int ldsByte = wv * 6144 + i * 1024 + lane * 16;
                int gByte = ldsByte ^ (((ldsByte >> 8) & 15) << 4);
                GLOAD_LDS16(gs + gByte,
                            (char*)&wlds[buf ^ 1][0] + wv * 6144 + i * 1024);
            }
        }
        if (active) {
            // Hoisted epilogue operands: issue loads before the MFMA cluster
            // so their latency hides under the matrix work.
            int ocol = cb * 16 + l15;
            float hv[4];
            #pragma unroll
            for (int reg = 0; reg < 4; ++reg)
                hv[reg] = hx[(size_t)(rowBase + quad * 4 + reg) * DIM + ocol];
            float bir = bi[ocol], biz = bi[128 + ocol], bin = bi[256 + ocol];
            float bhr = bh[ocol], bhz = bh[128 + ocol], bhn = bh[256 + ocol];

            f32x4v acc[6];
            #pragma unroll
            for (int g = 0; g < 6; ++g) acc[g] = (f32x4v){0.f, 0.f, 0.f, 0.f};
            const char* slab = (const char*)&wlds[buf][0];
            #pragma unroll
            for (int kst = 0; kst < 4; ++kst) {
                const int co = (((kst * 4 + quad) ^ l15) << 4);   // swizzled col
                #pragma unroll
                for (int g = 0; g < 3; ++g) {
                    bf16x8 bI = *(const bf16x8*)(slab + g * 4096 + l15 * 256 + co);
                    acc[g] = __builtin_amdgcn_mfma_f32_16x16x32_bf16(
                        aLo[kst], bI, acc[g], 0, 0, 0);
                    bf16x8 bH = *(const bf16x8*)(slab + (g + 3) * 4096 + l15 * 256 + co);
                    acc[g + 3] = __builtin_amdgcn_mfma_f32_16x16x32_bf16(
                        aHi[kst], bH, acc[g + 3], 0, 0, 0);
                }
            }
            #pragma unroll
            for (int reg = 0; reg < 4; ++reg) {
                int row = rowBase + quad * 4 + reg;
                float ir = acc[0][reg] + bir, iz = acc[1][reg] + biz, in_ = acc[2][reg] + bin;
                float hr = acc[3][reg] + bhr, hz = acc[4][reg] + bhz, hn = acc[5][reg] + bhn;
                float rg = 1.0f / (1.0f + __expf(-(ir + hr)));
                float zg = 1.0f / (1.0f + __expf(-(iz + hz)));
                float ng = tanhf(in_ + rg * hn);
                out[(size_t)row * DIM + ocol] = (1.0f - zg) * ng + zg * hv[reg];
            }
        }
        __syncthreads();   // drains this iter's prefetch; protects buf reuse
    }
}

// ---------------------------------------------------------------------------
extern "C" void kernel_launch(void* const* d_in, const int* in_sizes, int n_in,
                              void* d_out, int out_size, void* d_ws, size_t ws_size,
                              hipStream_t stream) {
    const float* feat = (const float*)d_in[0];
    const float* hx   = (const float*)d_in[1];
    const float* Wi   = (const float*)d_in[2];
    const float* bi   = (const float*)d_in[3];
    const float* Wh   = (const float*)d_in[4];
    const float* bh   = (const float*)d_in[5];
    const int* src    = (const int*)d_in[6];
    const int* dst    = (const int*)d_in[7];
    float* out        = (float*)d_out;

    int N = in_sizes[0] / DIM;   // 50000
    int E = in_sizes[6];         // 800000
    int Npad = (N + 1) & ~1;     // even stride for u16-pair word copies
    int chunk = (E + NCH - 1) / NCH;     // 25000 (< 65536 -> u16 counters)
    int NB    = (N + 255) / 256;         // 196 (<= 256 for the LDS scan)

    unsigned short* partI = (unsigned short*)d_ws;            // NCH*Npad u16
    unsigned short* partO = partI + (size_t)NCH * Npad;       // NCH*Npad u16
    int* csrOffC   = (int*)(partO + (size_t)NCH * Npad);      // NCH*N
    int* csrOff    = csrOffC + (size_t)NCH * N;               // N+1
    int* srcSorted = csrOff + N + 1;                          // E
    unsigned short* rank = (unsigned short*)(srcSorted + E);  // E u16
    int* bsum      = (int*)(rank + ((E + 1) & ~1));           // 256
    float* normIf  = (float*)(bsum + 256);                    // N
    float* normOf  = normIf + N;                              // N
    size_t iend = (size_t)(normOf + N - (float*)d_ws);
    size_t wofs = (iend * 4 + 15) & ~(size_t)15;
    short* Wbf = (short*)((char*)d_ws + wofs);                // 98304 bf16
    size_t fofs = (wofs + 98304 * 2 + 15) & ~(size_t)15;
    short* fh = (short*)((char*)d_ws + fofs);                 // N*256 bf16
    // total ws: ~45 MB (proven-safe budget: 51.6 MB)
    short* agg = (short*)d_out;  // bf16 agg aliased over d_out

    k_hist<<<2 * NCH, 1024, 0, stream>>>(src, dst, partO, partI, rank,
                                         N, Npad, E, chunk);
    k_bsum<<<NB, 256, 0, stream>>>(partI, bsum, N, Npad);
    k_off<<<NB, 256, 0, stream>>>(partI, partO, bsum, csrOffC, csrOff,
                                  normIf, normOf, N, Npad, NB);
    k_xcw<<<(N * 64 + 98304 + E + 255) / 256, 256, 0, stream>>>(
        feat, hx, Wi, Wh, normOf, Wbf, fh,
        src, dst, rank, csrOffC, srcSorted, N, E, chunk);

    gather_kernel<<<(N + 3) / 4, 256, 0, stream>>>(
        fh, csrOff, srcSorted, normIf, agg, N);
    gemm_gates_kernel<<<(N + 63) / 64, 256, 0, stream>>>(
        agg, hx, Wbf, bi, bh, out, N);
}